// Round 1
// baseline (168.337 us; speedup 1.0000x reference)
//
#include <hip/hip_runtime.h>
#include <math.h>

namespace {

constexpr int kB  = 4;
constexpr int kS  = 128;
constexpr int kD  = 256;
constexpr int kH  = 8;
constexpr int kDk = 32;
constexpr float kPi    = 3.14159265358979323846f;
constexpr float kScale = 0.17677669529663687f;  // 1/sqrt(32)

// ---------------- QKV projection: Q/K/V[n,d] = x[n,:] . W*[d,:] + b*[d] ----
__global__ void proj_qkv_kernel(const float* __restrict__ x,
                                const float* __restrict__ Wq, const float* __restrict__ bq,
                                const float* __restrict__ Wk, const float* __restrict__ bk,
                                const float* __restrict__ Wv, const float* __restrict__ bv,
                                float* __restrict__ Q, float* __restrict__ K,
                                float* __restrict__ V) {
  __shared__ float xs[kD];
  const int n = blockIdx.x;   // row 0..511
  const int t = threadIdx.x;  // col 0..255
  xs[t] = x[n * kD + t];
  __syncthreads();
  const float* wq = Wq + t * kD;
  const float* wk = Wk + t * kD;
  const float* wv = Wv + t * kD;
  float aq = 0.f, ak = 0.f, av = 0.f;
#pragma unroll 8
  for (int k = 0; k < kD; ++k) {
    const float xv = xs[k];
    aq = fmaf(xv, wq[k], aq);
    ak = fmaf(xv, wk[k], ak);
    av = fmaf(xv, wv[k], av);
  }
  Q[n * kD + t] = aq + bq[t];
  K[n * kD + t] = ak + bk[t];
  V[n * kD + t] = av + bv[t];
}

// ------------- normalize first-4 angles per (b,h,s); store cos/sin(ang/2) --
__global__ void trig_kernel(const float* __restrict__ Q, const float* __restrict__ K,
                            float* __restrict__ qt, float* __restrict__ kt) {
  const int idx = blockIdx.x * blockDim.x + threadIdx.x;  // (b,h,s)
  if (idx >= kB * kH * kS) return;
  const int s = idx % kS;
  const int h = (idx / kS) % kH;
  const int b = idx / (kS * kH);
  const float* qp = Q + ((b * kS + s) * kD + h * kDk);
  const float* kp = K + ((b * kS + s) * kD + h * kDk);
  float qv[4], kv[4];
#pragma unroll
  for (int w = 0; w < 4; ++w) { qv[w] = qp[w]; kv[w] = kp[w]; }
  const float qmn = fminf(fminf(qv[0], qv[1]), fminf(qv[2], qv[3]));
  const float qmx = fmaxf(fmaxf(qv[0], qv[1]), fmaxf(qv[2], qv[3]));
  const float kmn = fminf(fminf(kv[0], kv[1]), fminf(kv[2], kv[3]));
  const float kmx = fmaxf(fmaxf(kv[0], kv[1]), fmaxf(kv[2], kv[3]));
  const float qsc = kPi / (qmx - qmn + 1e-8f);
  const float ksc = kPi / (kmx - kmn + 1e-8f);
  float* qo = qt + idx * 8;
  float* ko = kt + idx * 8;
#pragma unroll
  for (int w = 0; w < 4; ++w) {
    const float qa = (qv[w] - qmn) * qsc * 0.5f;  // half-angle
    const float ka = (kv[w] - kmn) * ksc * 0.5f;
    qo[w * 2 + 0] = cosf(qa);
    qo[w * 2 + 1] = sinf(qa);
    ko[w * 2 + 0] = cosf(ka);
    ko[w * 2 + 1] = sinf(ka);
  }
}

// ----------- 4-qubit circuit sim per (b,h,i,j): product init, RX+CNOT ×4, <Z0>
__global__ void qscore_kernel(const float* __restrict__ qt, const float* __restrict__ kt,
                              const float* __restrict__ params,
                              float* __restrict__ scores) {
  const int tid = blockIdx.x * blockDim.x + threadIdx.x;
  if (tid >= kB * kH * kS * kS) return;
  const int j  = tid & (kS - 1);
  const int i  = (tid >> 7) & (kS - 1);
  const int bh = tid >> 14;
  const float* qp = qt + (bh * kS + i) * 8;
  const float* kp = kt + (bh * kS + j) * 8;

  // per-wire amplitudes:
  //   a0 = cos(q/2) e^{-ik/2} = cq*ck - i*cq*sk
  //   a1 = -i sin(q/2) e^{+ik/2} = sq*sk - i*sq*ck
  float a0r[4], a0i[4], a1r[4], a1i[4];
#pragma unroll
  for (int w = 0; w < 4; ++w) {
    const float cq = qp[w * 2], sq = qp[w * 2 + 1];
    const float ck = kp[w * 2], sk = kp[w * 2 + 1];
    a0r[w] = cq * ck;
    a0i[w] = -cq * sk;
    a1r[w] = sq * sk;
    a1i[w] = -sq * ck;
  }
  // product state; wire w lives at bit (3-w): idx = q0q1q2q3
  float sr[16], si[16];
#pragma unroll
  for (int idx = 0; idx < 16; ++idx) {
    float r = 1.f, im = 0.f;
#pragma unroll
    for (int w = 0; w < 4; ++w) {
      const int bit = (idx >> (3 - w)) & 1;
      const float pr = bit ? a1r[w] : a0r[w];
      const float pi = bit ? a1i[w] : a0i[w];
      const float nr = r * pr - im * pi;
      const float ni = r * pi + im * pr;
      r = nr; im = ni;
    }
    sr[idx] = r; si[idx] = im;
  }
  // circuit: for w: RX(params[w]) on wire w, then CNOT(w, (w+1)%4)
#pragma unroll
  for (int w = 0; w < 4; ++w) {
    const float half = params[w] * 0.5f;
    const float ct = cosf(half);
    const float st = sinf(half);  // gate elem is -i*st
    const int m = 1 << (3 - w);
#pragma unroll
    for (int idx = 0; idx < 16; ++idx) {
      if (idx & m) continue;
      const int p = idx | m;
      const float or0 = sr[idx], oi0 = si[idx];
      const float or1 = sr[p],  oi1 = si[p];
      // new0 = ct*old0 - i*st*old1 ; new1 = -i*st*old0 + ct*old1
      sr[idx] = fmaf(ct, or0,  st * oi1);
      si[idx] = fmaf(ct, oi0, -st * or1);
      sr[p]   = fmaf(st, oi0,  ct * or1);
      si[p]   = fmaf(-st, or0, ct * oi1);
    }
    const int w2 = (w + 1) & 3;
    const int mt = 1 << (3 - w2);
#pragma unroll
    for (int idx = 0; idx < 16; ++idx) {
      if ((idx & m) && !(idx & mt)) {
        const int p = idx | mt;
        const float tr = sr[idx]; sr[idx] = sr[p]; sr[p] = tr;
        const float ti = si[idx]; si[idx] = si[p]; si[p] = ti;
      }
    }
  }
  // <Z0>: + for bit3==0, - for bit3==1
  float ez = 0.f;
#pragma unroll
  for (int idx = 0; idx < 16; ++idx) {
    const float p2 = sr[idx] * sr[idx] + si[idx] * si[idx];
    ez += (idx & 8) ? -p2 : p2;
  }
  scores[tid] = ez;
}

// ---------------- softmax over j, in place, one block (128 thr) per row ----
__global__ void softmax_kernel(float* __restrict__ scores) {
  __shared__ float red[kS];
  const int row = blockIdx.x;
  const int t   = threadIdx.x;
  const float v = scores[row * kS + t] * kScale;
  red[t] = v;
  __syncthreads();
  for (int off = kS / 2; off > 0; off >>= 1) {
    if (t < off) red[t] = fmaxf(red[t], red[t + off]);
    __syncthreads();
  }
  const float mx = red[0];
  __syncthreads();
  const float e = expf(v - mx);
  red[t] = e;
  __syncthreads();
  for (int off = kS / 2; off > 0; off >>= 1) {
    if (t < off) red[t] += red[t + off];
    __syncthreads();
  }
  scores[row * kS + t] = e / red[0];
}

// ----- out[b,i,h*32+d] = sum_j attn[b,h,i,j] * V[b,j,h*32+d] ---------------
__global__ void attnv_kernel(const float* __restrict__ attn, const float* __restrict__ V,
                             float* __restrict__ out) {
  const int tid = blockIdx.x * blockDim.x + threadIdx.x;
  if (tid >= kB * kH * kS * kDk) return;
  const int d = tid & (kDk - 1);
  const int i = (tid >> 5) & (kS - 1);
  const int h = (tid >> 12) & (kH - 1);
  const int b = tid >> 15;
  const float* arow = attn + ((b * kH + h) * kS + i) * kS;
  const float* vp   = V + b * kS * kD + h * kDk + d;
  float acc = 0.f;
#pragma unroll 4
  for (int jj = 0; jj < kS; ++jj) acc = fmaf(arow[jj], vp[jj * kD], acc);
  out[(b * kS + i) * kD + h * kDk + d] = acc;
}

// ---------------- final projection: out = ao @ Wo.T + bo -------------------
__global__ void proj_o_kernel(const float* __restrict__ ao, const float* __restrict__ Wo,
                              const float* __restrict__ bo, float* __restrict__ out) {
  __shared__ float xs[kD];
  const int n = blockIdx.x;
  const int t = threadIdx.x;
  xs[t] = ao[n * kD + t];
  __syncthreads();
  const float* w = Wo + t * kD;
  float a = 0.f;
#pragma unroll 8
  for (int k = 0; k < kD; ++k) a = fmaf(xs[k], w[k], a);
  out[n * kD + t] = a + bo[t];
}

}  // namespace

extern "C" void kernel_launch(void* const* d_in, const int* in_sizes, int n_in,
                              void* d_out, int out_size, void* d_ws, size_t ws_size,
                              hipStream_t stream) {
  const float* x  = (const float*)d_in[0];
  const float* Wq = (const float*)d_in[1];
  const float* bq = (const float*)d_in[2];
  const float* Wk = (const float*)d_in[3];
  const float* bk = (const float*)d_in[4];
  const float* Wv = (const float*)d_in[5];
  const float* bv = (const float*)d_in[6];
  const float* Wo = (const float*)d_in[7];
  const float* bo = (const float*)d_in[8];
  const float* pr = (const float*)d_in[9];
  float* out = (float*)d_out;

  float* ws = (float*)d_ws;
  float* Q  = ws;             // 131072 floats
  float* K  = Q + 131072;     // 131072
  float* V  = K + 131072;     // 131072
  float* qt = V + 131072;     // 32768 (B*H*S*4 wires * {cos,sin})
  float* kt = qt + 32768;     // 32768
  float* sc = kt + 32768;     // 524288 (B*H*S*S)
  float* ao = sc + 524288;    // 131072
  // total 1114112 floats = ~4.25 MB of d_ws

  proj_qkv_kernel<<<kB * kS, kD, 0, stream>>>(x, Wq, bq, Wk, bk, Wv, bv, Q, K, V);
  trig_kernel<<<(kB * kH * kS + 255) / 256, 256, 0, stream>>>(Q, K, qt, kt);
  qscore_kernel<<<(kB * kH * kS * kS) / 256, 256, 0, stream>>>(qt, kt, pr, sc);
  softmax_kernel<<<kB * kH * kS, kS, 0, stream>>>(sc);
  attnv_kernel<<<(kB * kH * kS * kDk) / 256, 256, 0, stream>>>(sc, V, ao);
  proj_o_kernel<<<kB * kS, kD, 0, stream>>>(ao, Wo, bo, out);
}

// Round 3
// 115.444 us; speedup vs baseline: 1.4582x; 1.4582x over previous
//
#include <hip/hip_runtime.h>
#include <math.h>

namespace {

constexpr int kB  = 4;
constexpr int kS  = 128;
constexpr int kD  = 256;
constexpr int kH  = 8;
constexpr int kDk = 32;
constexpr int kK  = 256;
constexpr float kPi    = 3.14159265358979323846f;
constexpr float kScale = 0.17677669529663687f;  // 1/sqrt(32)

typedef __bf16 bf16x8 __attribute__((ext_vector_type(8)));
typedef float  f32x4  __attribute__((ext_vector_type(4)));

// ---- split fp32 -> (hi, lo) bf16 for x, Wq/Wk/Wv (packed), and Wo ---------
__global__ void convert_xw_kernel(const float* __restrict__ x,
                                  const float* __restrict__ Wq, const float* __restrict__ Wk,
                                  const float* __restrict__ Wv, const float* __restrict__ Wo,
                                  __bf16* __restrict__ xhi, __bf16* __restrict__ xlo,
                                  __bf16* __restrict__ wqkvhi, __bf16* __restrict__ wqkvlo,
                                  __bf16* __restrict__ wohi, __bf16* __restrict__ wolo) {
  const int idx = blockIdx.x * 256 + threadIdx.x;  // 0 .. 393215
  float v;
  __bf16 *dh, *dl;
  int o;
  if (idx < 131072) {
    v = x[idx]; dh = xhi; dl = xlo; o = idx;
  } else {
    const int wi = idx - 131072;          // 0 .. 262143
    const int m  = wi >> 16;              // which W
    const int r  = wi & 65535;
    if (m == 0)      { v = Wq[r]; dh = wqkvhi; dl = wqkvlo; o = wi; }
    else if (m == 1) { v = Wk[r]; dh = wqkvhi; dl = wqkvlo; o = wi; }
    else if (m == 2) { v = Wv[r]; dh = wqkvhi; dl = wqkvlo; o = wi; }
    else             { v = Wo[r]; dh = wohi;   dl = wolo;   o = r;  }
  }
  const __bf16 h = (__bf16)v;
  dh[o] = h;
  dl[o] = (__bf16)(v - (float)h);
}

__global__ void convert_ao_kernel(const float* __restrict__ src,
                                  __bf16* __restrict__ hi, __bf16* __restrict__ lo) {
  const int idx = blockIdx.x * 256 + threadIdx.x;  // 131072
  const float v = src[idx];
  const __bf16 h = (__bf16)v;
  hi[idx] = h;
  lo[idx] = (__bf16)(v - (float)h);
}

// ---- bf16x3 MFMA GEMM: out[m,n] = sum_k A[m,k] * W[n,k] + bias[n] ---------
// A: M=512 x K=256 (hi/lo); W: one 256x256 matrix per blockIdx.z (hi/lo).
// grid: (M/16, N/64, nmat); block 256 = 4 waves, wave w handles n-subtile w.
// Fragment layouts (m89/m120-verified):
//   A[m=lane&15][k=quad*8+j], B[k=quad*8+j][n=lane&15],
//   C/D: col(n)=lane&15, row(m)=quad*4+reg.
__global__ void gemm_bf16x3_kernel(const __bf16* __restrict__ ahi, const __bf16* __restrict__ alo,
                                   const __bf16* __restrict__ whi, const __bf16* __restrict__ wlo,
                                   const float* __restrict__ b0, const float* __restrict__ b1,
                                   const float* __restrict__ b2,
                                   float* __restrict__ obase) {
  const int z = blockIdx.z;
  const __bf16* bh = whi + z * 65536;
  const __bf16* bl = wlo + z * 65536;
  const float* bias = (z == 0) ? b0 : (z == 1) ? b1 : b2;
  float* out = obase + z * 131072;

  const int wave = threadIdx.x >> 6;
  const int lane = threadIdx.x & 63;
  const int ln = lane & 15;
  const int qd = lane >> 4;
  const int m0 = blockIdx.x * 16;
  const int n0 = blockIdx.y * 64 + wave * 16;

  const __bf16* ap  = ahi + (m0 + ln) * kK + qd * 8;
  const __bf16* alp = alo + (m0 + ln) * kK + qd * 8;
  const __bf16* bp  = bh  + (n0 + ln) * kK + qd * 8;
  const __bf16* blp = bl  + (n0 + ln) * kK + qd * 8;

  f32x4 acc = {0.f, 0.f, 0.f, 0.f};
#pragma unroll
  for (int kc = 0; kc < kK; kc += 32) {
    const bf16x8 Ah = *(const bf16x8*)(ap  + kc);
    const bf16x8 Al = *(const bf16x8*)(alp + kc);
    const bf16x8 Bh = *(const bf16x8*)(bp  + kc);
    const bf16x8 Bl = *(const bf16x8*)(blp + kc);
    acc = __builtin_amdgcn_mfma_f32_16x16x32_bf16(Ah, Bh, acc, 0, 0, 0);
    acc = __builtin_amdgcn_mfma_f32_16x16x32_bf16(Ah, Bl, acc, 0, 0, 0);
    acc = __builtin_amdgcn_mfma_f32_16x16x32_bf16(Al, Bh, acc, 0, 0, 0);
  }
  const int col  = n0 + ln;
  const float bv = bias[col];
  const int row0 = m0 + qd * 4;
#pragma unroll
  for (int r = 0; r < 4; ++r)
    out[(row0 + r) * kD + col] = acc[r] + bv;
}

// ------------- normalize first-4 angles per (b,h,s); store cos/sin(ang/2) --
__global__ void trig_kernel(const float* __restrict__ Q, const float* __restrict__ K,
                            float* __restrict__ qt, float* __restrict__ kt) {
  const int idx = blockIdx.x * blockDim.x + threadIdx.x;  // (b,h,s)
  if (idx >= kB * kH * kS) return;
  const int s = idx % kS;
  const int h = (idx / kS) % kH;
  const int b = idx / (kS * kH);
  const float* qp = Q + ((b * kS + s) * kD + h * kDk);
  const float* kp = K + ((b * kS + s) * kD + h * kDk);
  float qv[4], kv[4];
#pragma unroll
  for (int w = 0; w < 4; ++w) { qv[w] = qp[w]; kv[w] = kp[w]; }
  const float qmn = fminf(fminf(qv[0], qv[1]), fminf(qv[2], qv[3]));
  const float qmx = fmaxf(fmaxf(qv[0], qv[1]), fmaxf(qv[2], qv[3]));
  const float kmn = fminf(fminf(kv[0], kv[1]), fminf(kv[2], kv[3]));
  const float kmx = fmaxf(fmaxf(kv[0], kv[1]), fmaxf(kv[2], kv[3]));
  const float qsc = kPi / (qmx - qmn + 1e-8f);
  const float ksc = kPi / (kmx - kmn + 1e-8f);
  float* qo = qt + idx * 8;
  float* ko = kt + idx * 8;
#pragma unroll
  for (int w = 0; w < 4; ++w) {
    const float qa = (qv[w] - qmn) * qsc * 0.5f;  // half-angle
    const float ka = (kv[w] - kmn) * ksc * 0.5f;
    qo[w * 2 + 0] = cosf(qa);
    qo[w * 2 + 1] = sinf(qa);
    ko[w * 2 + 0] = cosf(ka);
    ko[w * 2 + 1] = sinf(ka);
  }
}

// ----------- 4-qubit circuit sim per (b,h,i,j): product init, RX+CNOT ×4, <Z0>
__global__ void qscore_kernel(const float* __restrict__ qt, const float* __restrict__ kt,
                              const float* __restrict__ params,
                              float* __restrict__ scores) {
  const int tid = blockIdx.x * blockDim.x + threadIdx.x;
  if (tid >= kB * kH * kS * kS) return;
  const int j  = tid & (kS - 1);
  const int i  = (tid >> 7) & (kS - 1);
  const int bh = tid >> 14;
  const float* qp = qt + (bh * kS + i) * 8;
  const float* kp = kt + (bh * kS + j) * 8;

  float a0r[4], a0i[4], a1r[4], a1i[4];
#pragma unroll
  for (int w = 0; w < 4; ++w) {
    const float cq = qp[w * 2], sq = qp[w * 2 + 1];
    const float ck = kp[w * 2], sk = kp[w * 2 + 1];
    a0r[w] = cq * ck;
    a0i[w] = -cq * sk;
    a1r[w] = sq * sk;
    a1i[w] = -sq * ck;
  }
  float sr[16], si[16];
#pragma unroll
  for (int idx = 0; idx < 16; ++idx) {
    float r = 1.f, im = 0.f;
#pragma unroll
    for (int w = 0; w < 4; ++w) {
      const int bit = (idx >> (3 - w)) & 1;
      const float pr = bit ? a1r[w] : a0r[w];
      const float pi = bit ? a1i[w] : a0i[w];
      const float nr = r * pr - im * pi;
      const float ni = r * pi + im * pr;
      r = nr; im = ni;
    }
    sr[idx] = r; si[idx] = im;
  }
#pragma unroll
  for (int w = 0; w < 4; ++w) {
    const float half = params[w] * 0.5f;
    const float ct = cosf(half);
    const float st = sinf(half);
    const int m = 1 << (3 - w);
#pragma unroll
    for (int idx = 0; idx < 16; ++idx) {
      if (idx & m) continue;
      const int p = idx | m;
      const float or0 = sr[idx], oi0 = si[idx];
      const float or1 = sr[p],  oi1 = si[p];
      sr[idx] = fmaf(ct, or0,  st * oi1);
      si[idx] = fmaf(ct, oi0, -st * or1);
      sr[p]   = fmaf(st, oi0,  ct * or1);
      si[p]   = fmaf(-st, or0, ct * oi1);
    }
    const int w2 = (w + 1) & 3;
    const int mt = 1 << (3 - w2);
#pragma unroll
    for (int idx = 0; idx < 16; ++idx) {
      if ((idx & m) && !(idx & mt)) {
        const int p = idx | mt;
        const float tr = sr[idx]; sr[idx] = sr[p]; sr[p] = tr;
        const float ti = si[idx]; si[idx] = si[p]; si[p] = ti;
      }
    }
  }
  float ez = 0.f;
#pragma unroll
  for (int idx = 0; idx < 16; ++idx) {
    const float p2 = sr[idx] * sr[idx] + si[idx] * si[idx];
    ez += (idx & 8) ? -p2 : p2;
  }
  scores[tid] = ez;
}

// ---------------- softmax over j, in place, one block (128 thr) per row ----
__global__ void softmax_kernel(float* __restrict__ scores) {
  __shared__ float red[kS];
  const int row = blockIdx.x;
  const int t   = threadIdx.x;
  const float v = scores[row * kS + t] * kScale;
  red[t] = v;
  __syncthreads();
  for (int off = kS / 2; off > 0; off >>= 1) {
    if (t < off) red[t] = fmaxf(red[t], red[t + off]);
    __syncthreads();
  }
  const float mx = red[0];
  __syncthreads();
  const float e = expf(v - mx);
  red[t] = e;
  __syncthreads();
  for (int off = kS / 2; off > 0; off >>= 1) {
    if (t < off) red[t] += red[t + off];
    __syncthreads();
  }
  scores[row * kS + t] = e / red[0];
}

// ----- ao[b,i,h*32+d] = sum_j attn[b,h,i,j] * V[b,j,h*32+d] ----------------
__global__ void attnv_kernel(const float* __restrict__ attn, const float* __restrict__ V,
                             float* __restrict__ out) {
  const int tid = blockIdx.x * blockDim.x + threadIdx.x;
  if (tid >= kB * kH * kS * kDk) return;
  const int d = tid & (kDk - 1);
  const int i = (tid >> 5) & (kS - 1);
  const int h = (tid >> 12) & (kH - 1);
  const int b = tid >> 15;
  const float* arow = attn + ((b * kH + h) * kS + i) * kS;
  const float* vp   = V + b * kS * kD + h * kDk + d;
  float acc = 0.f;
#pragma unroll 4
  for (int jj = 0; jj < kS; ++jj) acc = fmaf(arow[jj], vp[jj * kD], acc);
  out[(b * kS + i) * kD + h * kDk + d] = acc;
}

}  // namespace

extern "C" void kernel_launch(void* const* d_in, const int* in_sizes, int n_in,
                              void* d_out, int out_size, void* d_ws, size_t ws_size,
                              hipStream_t stream) {
  const float* x  = (const float*)d_in[0];
  const float* Wq = (const float*)d_in[1];
  const float* bq = (const float*)d_in[2];
  const float* Wk = (const float*)d_in[3];
  const float* bk = (const float*)d_in[4];
  const float* Wv = (const float*)d_in[5];
  const float* bv = (const float*)d_in[6];
  const float* Wo = (const float*)d_in[7];
  const float* bo = (const float*)d_in[8];
  const float* pr = (const float*)d_in[9];
  float* out = (float*)d_out;

  // -------- workspace layout (floats) --------
  // Dedicated (never aliased):
  //   Q 131072 | K 131072 | V 131072 | qt 32768 | kt 32768 | sc 524288
  //   | ao 131072 | wo_hi+lo 65536   -> total 1179648 floats = 4.5 MB
  float* ws = (float*)d_ws;
  float* Q  = ws;
  float* K  = Q + 131072;
  float* V  = K + 131072;
  float* qt = V + 131072;
  float* kt = qt + 32768;
  float* sc = kt + 32768;      // 524288 floats (B*H*S*S)
  float* ao = sc + 524288;
  __bf16* wohi = (__bf16*)(ao + 131072);  // 65536 bf16
  __bf16* wolo = wohi + 65536;            // 65536 bf16 (ends at 4.5 MB)

  // Aliased into sc, lifetimes end before qscore writes sc:
  //   xhi/xlo: 131072 bf16 each; wqkv hi/lo: 196608 bf16 each
  //   total 327680 floats <= 524288. Dead after gemm-qkv.
  __bf16* xhi    = (__bf16*)sc;           // 131072 bf16
  __bf16* xlo    = xhi + 131072;
  __bf16* wqkvhi = xlo + 131072;          // 196608 bf16 (Wq|Wk|Wv)
  __bf16* wqkvlo = wqkvhi + 196608;       // ends at float-offset 327680
  // Aliased into sc AFTER attnv's last read of sc:
  __bf16* aohi = (__bf16*)sc;             // 131072 bf16
  __bf16* aolo = aohi + 131072;

  convert_xw_kernel<<<1536, 256, 0, stream>>>(x, Wq, Wk, Wv, Wo,
                                              xhi, xlo, wqkvhi, wqkvlo, wohi, wolo);
  gemm_bf16x3_kernel<<<dim3(32, 4, 3), 256, 0, stream>>>(xhi, xlo, wqkvhi, wqkvlo,
                                                         bq, bk, bv, Q);
  trig_kernel<<<(kB * kH * kS + 255) / 256, 256, 0, stream>>>(Q, K, qt, kt);
  qscore_kernel<<<(kB * kH * kS * kS) / 256, 256, 0, stream>>>(qt, kt, pr, sc);
  softmax_kernel<<<kB * kH * kS, kS, 0, stream>>>(sc);
  attnv_kernel<<<(kB * kH * kS * kDk) / 256, 256, 0, stream>>>(sc, V, ao);
  convert_ao_kernel<<<512, 256, 0, stream>>>(ao, aohi, aolo);
  gemm_bf16x3_kernel<<<dim3(32, 4, 1), 256, 0, stream>>>(aohi, aolo, wohi, wolo,
                                                         bo, bo, bo, out);
}

// Round 4
// 96.734 us; speedup vs baseline: 1.7402x; 1.1934x over previous
//
#include <hip/hip_runtime.h>
#include <math.h>

namespace {

constexpr int kB  = 4;
constexpr int kS  = 128;
constexpr int kD  = 256;
constexpr int kH  = 8;
constexpr int kK  = 256;
constexpr float kPi    = 3.14159265358979323846f;
constexpr float kScale = 0.17677669529663687f;  // 1/sqrt(32)

typedef __bf16 bf16x8 __attribute__((ext_vector_type(8)));
typedef float  f32x4  __attribute__((ext_vector_type(4)));

// ---- split fp32 -> (hi, lo) bf16 for x, Wq/Wk/Wv (packed), and Wo ---------
__global__ void convert_xw_kernel(const float* __restrict__ x,
                                  const float* __restrict__ Wq, const float* __restrict__ Wk,
                                  const float* __restrict__ Wv, const float* __restrict__ Wo,
                                  __bf16* __restrict__ xhi, __bf16* __restrict__ xlo,
                                  __bf16* __restrict__ wqkvhi, __bf16* __restrict__ wqkvlo,
                                  __bf16* __restrict__ wohi, __bf16* __restrict__ wolo) {
  const int idx = blockIdx.x * 256 + threadIdx.x;  // 0 .. 393215
  float v;
  __bf16 *dh, *dl;
  int o;
  if (idx < 131072) {
    v = x[idx]; dh = xhi; dl = xlo; o = idx;
  } else {
    const int wi = idx - 131072;          // 0 .. 262143
    const int m  = wi >> 16;              // which W
    const int r  = wi & 65535;
    if (m == 0)      { v = Wq[r]; dh = wqkvhi; dl = wqkvlo; o = wi; }
    else if (m == 1) { v = Wk[r]; dh = wqkvhi; dl = wqkvlo; o = wi; }
    else if (m == 2) { v = Wv[r]; dh = wqkvhi; dl = wqkvlo; o = wi; }
    else             { v = Wo[r]; dh = wohi;   dl = wolo;   o = r;  }
  }
  const __bf16 h = (__bf16)v;
  dh[o] = h;
  dl[o] = (__bf16)(v - (float)h);
}

// ---- bf16x3 MFMA GEMM: out[m,n] = sum_k A[m,k] * W[n,k] + bias[n] ---------
// Fragment layouts (m89/m120-verified):
//   A[m=lane&15][k=quad*8+j], B[k=quad*8+j][n=lane&15],
//   C/D: col(n)=lane&15, row(m)=quad*4+reg.
__global__ void gemm_bf16x3_kernel(const __bf16* __restrict__ ahi, const __bf16* __restrict__ alo,
                                   const __bf16* __restrict__ whi, const __bf16* __restrict__ wlo,
                                   const float* __restrict__ b0, const float* __restrict__ b1,
                                   const float* __restrict__ b2,
                                   float* __restrict__ obase) {
  const int z = blockIdx.z;
  const __bf16* bh = whi + z * 65536;
  const __bf16* bl = wlo + z * 65536;
  const float* bias = (z == 0) ? b0 : (z == 1) ? b1 : b2;
  float* out = obase + z * 131072;

  const int wave = threadIdx.x >> 6;
  const int lane = threadIdx.x & 63;
  const int ln = lane & 15;
  const int qd = lane >> 4;
  const int m0 = blockIdx.x * 16;
  const int n0 = blockIdx.y * 64 + wave * 16;

  const __bf16* ap  = ahi + (m0 + ln) * kK + qd * 8;
  const __bf16* alp = alo + (m0 + ln) * kK + qd * 8;
  const __bf16* bp  = bh  + (n0 + ln) * kK + qd * 8;
  const __bf16* blp = bl  + (n0 + ln) * kK + qd * 8;

  f32x4 acc = {0.f, 0.f, 0.f, 0.f};
#pragma unroll
  for (int kc = 0; kc < kK; kc += 32) {
    const bf16x8 Ah = *(const bf16x8*)(ap  + kc);
    const bf16x8 Al = *(const bf16x8*)(alp + kc);
    const bf16x8 Bh = *(const bf16x8*)(bp  + kc);
    const bf16x8 Bl = *(const bf16x8*)(blp + kc);
    acc = __builtin_amdgcn_mfma_f32_16x16x32_bf16(Ah, Bh, acc, 0, 0, 0);
    acc = __builtin_amdgcn_mfma_f32_16x16x32_bf16(Ah, Bl, acc, 0, 0, 0);
    acc = __builtin_amdgcn_mfma_f32_16x16x32_bf16(Al, Bh, acc, 0, 0, 0);
  }
  const int col  = n0 + ln;
  const float bv = bias[col];
  const int row0 = m0 + qd * 4;
#pragma unroll
  for (int r = 0; r < 4; ++r)
    out[(row0 + r) * kD + col] = acc[r] + bv;
}

// ---- prep: per (b,h,s) closed-form score factors -------------------------
// E(i,j) = prod_{w=1..3} ( cos(th_w)cos(qn_w^i) - sin(th_w)sin(qn_w^i)cos(kn_w^j) )
//        = prod_w ( A_w^i - B_w^i * C_w^j )
// qn/kn are the pi-normalized angles (min/max over ALL 4 wires).
__global__ void prep_kernel(const float* __restrict__ Q, const float* __restrict__ K,
                            const float* __restrict__ params,
                            float* __restrict__ qprep,   // [4096][8]: A1..A3,B1..B3
                            float* __restrict__ kprep) { // [4096][4]: C1..C3
  const int idx = blockIdx.x * 256 + threadIdx.x;  // (bh, s)
  if (idx >= kB * kH * kS) return;
  const int s  = idx & (kS - 1);
  const int bh = idx >> 7;
  const int b  = bh >> 3;
  const int h  = bh & 7;
  const float4 qv = *(const float4*)(Q + (b * kS + s) * kD + h * 32);
  const float4 kv = *(const float4*)(K + (b * kS + s) * kD + h * 32);

  const float qmn = fminf(fminf(qv.x, qv.y), fminf(qv.z, qv.w));
  const float qmx = fmaxf(fmaxf(qv.x, qv.y), fmaxf(qv.z, qv.w));
  const float kmn = fminf(fminf(kv.x, kv.y), fminf(kv.z, kv.w));
  const float kmx = fmaxf(fmaxf(kv.x, kv.y), fmaxf(kv.z, kv.w));
  const float qsc = kPi / (qmx - qmn + 1e-8f);
  const float ksc = kPi / (kmx - kmn + 1e-8f);

  const float qn[3] = {(qv.y - qmn) * qsc, (qv.z - qmn) * qsc, (qv.w - qmn) * qsc};
  const float kn[3] = {(kv.y - kmn) * ksc, (kv.z - kmn) * ksc, (kv.w - kmn) * ksc};

  float* qo = qprep + idx * 8;
  float* ko = kprep + idx * 4;
#pragma unroll
  for (int w = 0; w < 3; ++w) {
    const float th = params[w + 1];
    const float ct = cosf(th), st = sinf(th);
    qo[w]     = ct * cosf(qn[w]);
    qo[w + 3] = st * sinf(qn[w]);
    ko[w]     = cosf(kn[w]);
  }
}

// ---- fused scores + softmax + attn@V, bf16-split epilogue -----------------
// grid: (8 i-tiles, 32 bh); block 256.
__global__ void fused_attn_kernel(const float* __restrict__ qprep,
                                  const float* __restrict__ kprep,
                                  const float* __restrict__ V,
                                  __bf16* __restrict__ aohi, __bf16* __restrict__ aolo) {
  __shared__ float kC[3][kS];        // C_w per j
  __shared__ float Vl[kS][32];       // V tile for this (b,h)
  __shared__ float pl[16][kS + 4];   // attention probs (padded)

  const int bh = blockIdx.y;
  const int i0 = blockIdx.x * 16;
  const int b  = bh >> 3;
  const int h  = bh & 7;
  const int tid = threadIdx.x;

  if (tid < kS) {
    const float4 c = *(const float4*)(kprep + (bh * kS + tid) * 4);
    kC[0][tid] = c.x; kC[1][tid] = c.y; kC[2][tid] = c.z;
  }
  {
    const int j0 = tid >> 5, d = tid & 31;
#pragma unroll
    for (int r = 0; r < 16; ++r) {
      const int j = r * 8 + j0;
      Vl[j][d] = V[(b * kS + j) * kD + h * 32 + d];
    }
  }
  __syncthreads();

  const int i_loc = tid >> 4;   // 0..15
  const int jl    = tid & 15;   // 16 threads per row
  const float* qp = qprep + (bh * kS + i0 + i_loc) * 8;
  const float A1 = qp[0], A2 = qp[1], A3 = qp[2];
  const float B1 = qp[3], B2 = qp[4], B3 = qp[5];

  float e[8];
  float mx = -1e30f;
#pragma unroll
  for (int jj = 0; jj < 8; ++jj) {
    const int j = jl + 16 * jj;
    const float v = (A1 - B1 * kC[0][j]) * (A2 - B2 * kC[1][j]) *
                    (A3 - B3 * kC[2][j]) * kScale;
    e[jj] = v;
    mx = fmaxf(mx, v);
  }
#pragma unroll
  for (int m = 1; m < 16; m <<= 1) mx = fmaxf(mx, __shfl_xor(mx, m, 16));
  float sum = 0.f;
#pragma unroll
  for (int jj = 0; jj < 8; ++jj) { e[jj] = expf(e[jj] - mx); sum += e[jj]; }
#pragma unroll
  for (int m = 1; m < 16; m <<= 1) sum += __shfl_xor(sum, m, 16);
  const float inv = 1.f / sum;
#pragma unroll
  for (int jj = 0; jj < 8; ++jj) pl[i_loc][jl + 16 * jj] = e[jj] * inv;
  __syncthreads();

  // attn @ V: thread -> (i = tid>>4, d0 = tid&15, and d0+16)
  const int d0 = tid & 15;
  float a0 = 0.f, a1 = 0.f;
#pragma unroll 4
  for (int j = 0; j < kS; ++j) {
    const float p = pl[i_loc][j];
    a0 = fmaf(p, Vl[j][d0], a0);
    a1 = fmaf(p, Vl[j][d0 + 16], a1);
  }
  const int base = (b * kS + i0 + i_loc) * kD + h * 32;
  const __bf16 h0 = (__bf16)a0;
  const __bf16 h1 = (__bf16)a1;
  aohi[base + d0]      = h0;
  aolo[base + d0]      = (__bf16)(a0 - (float)h0);
  aohi[base + d0 + 16] = h1;
  aolo[base + d0 + 16] = (__bf16)(a1 - (float)h1);
}

}  // namespace

extern "C" void kernel_launch(void* const* d_in, const int* in_sizes, int n_in,
                              void* d_out, int out_size, void* d_ws, size_t ws_size,
                              hipStream_t stream) {
  const float* x  = (const float*)d_in[0];
  const float* Wq = (const float*)d_in[1];
  const float* bq = (const float*)d_in[2];
  const float* Wk = (const float*)d_in[3];
  const float* bk = (const float*)d_in[4];
  const float* Wv = (const float*)d_in[5];
  const float* bv = (const float*)d_in[6];
  const float* Wo = (const float*)d_in[7];
  const float* bo = (const float*)d_in[8];
  const float* pr = (const float*)d_in[9];
  float* out = (float*)d_out;

  // -------- workspace layout (floats), all dedicated, no aliasing --------
  float* ws = (float*)d_ws;
  float* Q      = ws;               // 131072
  float* K      = Q + 131072;       // 131072
  float* V      = K + 131072;       // 131072
  float* qprep  = V + 131072;       // 32768
  float* kprep  = qprep + 32768;    // 16384
  float* f      = kprep + 16384;
  __bf16* xhi    = (__bf16*)f;            // 131072 bf16
  __bf16* xlo    = xhi + 131072;          // 131072
  __bf16* wqkvhi = xlo + 131072;          // 196608
  __bf16* wqkvlo = wqkvhi + 196608;       // 196608
  __bf16* wohi   = wqkvlo + 196608;       // 65536
  __bf16* wolo   = wohi + 65536;          // 65536
  __bf16* aohi   = wolo + 65536;          // 131072
  __bf16* aolo   = aohi + 131072;         // 131072
  // total ~4.2 MB << ws_size

  convert_xw_kernel<<<1536, 256, 0, stream>>>(x, Wq, Wk, Wv, Wo,
                                              xhi, xlo, wqkvhi, wqkvlo, wohi, wolo);
  gemm_bf16x3_kernel<<<dim3(32, 4, 3), 256, 0, stream>>>(xhi, xlo, wqkvhi, wqkvlo,
                                                         bq, bk, bv, Q);
  prep_kernel<<<16, 256, 0, stream>>>(Q, K, pr, qprep, kprep);
  fused_attn_kernel<<<dim3(8, 32), 256, 0, stream>>>(qprep, kprep, V, aohi, aolo);
  gemm_bf16x3_kernel<<<dim3(32, 4, 1), 256, 0, stream>>>(aohi, aolo, wohi, wolo,
                                                         bo, bo, bo, out);
}

// Round 5
// 88.090 us; speedup vs baseline: 1.9110x; 1.0981x over previous
//
#include <hip/hip_runtime.h>
#include <math.h>

namespace {

constexpr int kB  = 4;
constexpr int kS  = 128;
constexpr int kD  = 256;
constexpr int kH  = 8;
constexpr int kK  = 256;
constexpr float kPi    = 3.14159265358979323846f;
constexpr float kScale = 0.17677669529663687f;  // 1/sqrt(32)

typedef __bf16 bf16x8 __attribute__((ext_vector_type(8)));
typedef float  f32x4  __attribute__((ext_vector_type(4)));
typedef float  f32x8  __attribute__((ext_vector_type(8)));

// split 8 consecutive fp32 into bf16 hi/lo fragments (in registers)
__device__ inline void split8(const float* __restrict__ p, bf16x8& hi, bf16x8& lo) {
  const f32x8 v = *(const f32x8*)p;
#pragma unroll
  for (int e = 0; e < 8; ++e) {
    const __bf16 h = (__bf16)v[e];
    hi[e] = h;
    lo[e] = (__bf16)(v[e] - (float)h);
  }
}

// ---- K1: QKV projection via bf16x3 MFMA, inline fp32->bf16 split ----------
// grid (32 m-tiles, 5): ny<4 -> V cols ny*64+wave*16+ln (full 256 cols of Wv);
// ny==4 -> compact Qsub/Ksub: wave0/1 = Qsub cols 0..31, wave2/3 = Ksub,
//          compact col c maps to weight row head*32+wire (head=c>>2, wire=c&3).
// Fragment layouts (m89/m120-verified): A[m=lane&15][k=quad*8+j],
// B[k=quad*8+j][n=lane&15], C/D col(n)=lane&15, row(m)=quad*4+reg.
__global__ void qkv_kernel(const float* __restrict__ x,
                           const float* __restrict__ Wq, const float* __restrict__ bq,
                           const float* __restrict__ Wk, const float* __restrict__ bk,
                           const float* __restrict__ Wv, const float* __restrict__ bv,
                           float* __restrict__ V, float* __restrict__ Qs,
                           float* __restrict__ Ks) {
  const int wave = threadIdx.x >> 6;
  const int lane = threadIdx.x & 63;
  const int ln = lane & 15;
  const int qd = lane >> 4;
  const int m0 = blockIdx.x * 16;
  const int ny = blockIdx.y;

  const float* W;
  const float* bias;
  int wrow;
  if (ny < 4) {
    W = Wv; bias = bv;
    wrow = ny * 64 + wave * 16 + ln;
  } else {
    const int c = (wave & 1) * 16 + ln;   // compact col 0..31
    wrow = (c >> 2) * 32 + (c & 3);       // head*32 + wire
    if (wave < 2) { W = Wq; bias = bq; } else { W = Wk; bias = bk; }
  }

  const float* ap = x + (m0 + ln) * kK + qd * 8;
  const float* bp = W + wrow * kK + qd * 8;

  f32x4 acc = {0.f, 0.f, 0.f, 0.f};
#pragma unroll
  for (int kc = 0; kc < kK; kc += 32) {
    bf16x8 Ah, Al, Bh, Bl;
    split8(ap + kc, Ah, Al);
    split8(bp + kc, Bh, Bl);
    acc = __builtin_amdgcn_mfma_f32_16x16x32_bf16(Ah, Bh, acc, 0, 0, 0);
    acc = __builtin_amdgcn_mfma_f32_16x16x32_bf16(Ah, Bl, acc, 0, 0, 0);
    acc = __builtin_amdgcn_mfma_f32_16x16x32_bf16(Al, Bh, acc, 0, 0, 0);
  }
  const float bvv = bias[wrow];
  const int row0 = m0 + qd * 4;
  if (ny < 4) {
    const int col = ny * 64 + wave * 16 + ln;
#pragma unroll
    for (int r = 0; r < 4; ++r)
      V[(row0 + r) * kD + col] = acc[r] + bvv;
  } else {
    const int c = (wave & 1) * 16 + ln;
    float* o = (wave < 2) ? Qs : Ks;
#pragma unroll
    for (int r = 0; r < 4; ++r)
      o[(row0 + r) * 32 + c] = acc[r] + bvv;
  }
}

// ---- K2: fused prep + scores + softmax + attn@V, bf16-split epilogue ------
// Closed form (Pauli pull-back, verified R4):
//   E(i,j) = prod_{w=1..3} ( A_w^i - B_w^i * C_w^j ),
//   A_w = cos(th_w)cos(qn_w), B_w = sin(th_w)sin(qn_w), C_w = cos(kn_w);
//   qn/kn = pi-normalized angles (min/max over all 4 wires).
// grid (8 i-tiles, 32 bh), 256 threads.
__global__ void fused_attn_kernel(const float* __restrict__ Qs,
                                  const float* __restrict__ Ks,
                                  const float* __restrict__ V,
                                  const float* __restrict__ params,
                                  __bf16* __restrict__ aohi, __bf16* __restrict__ aolo) {
  __shared__ float kC[3][kS];
  __shared__ float Vl[kS][32];
  __shared__ float pl[16][kS + 4];
  __shared__ float qA[16][3], qB[16][3];

  const int bh = blockIdx.y;
  const int i0 = blockIdx.x * 16;
  const int b  = bh >> 3;
  const int h  = bh & 7;
  const int tid = threadIdx.x;

  if (tid < kS) {  // K-prep: one j per thread
    const float4 kv = *(const float4*)(Ks + (b * kS + tid) * 32 + h * 4);
    const float kmn = fminf(fminf(kv.x, kv.y), fminf(kv.z, kv.w));
    const float kmx = fmaxf(fmaxf(kv.x, kv.y), fmaxf(kv.z, kv.w));
    const float ksc = kPi / (kmx - kmn + 1e-8f);
    kC[0][tid] = cosf((kv.y - kmn) * ksc);
    kC[1][tid] = cosf((kv.z - kmn) * ksc);
    kC[2][tid] = cosf((kv.w - kmn) * ksc);
  } else if (tid < kS + 16) {  // Q-prep: one i per thread
    const int il = tid - kS;
    const float4 qv = *(const float4*)(Qs + (b * kS + i0 + il) * 32 + h * 4);
    const float qmn = fminf(fminf(qv.x, qv.y), fminf(qv.z, qv.w));
    const float qmx = fmaxf(fmaxf(qv.x, qv.y), fmaxf(qv.z, qv.w));
    const float qsc = kPi / (qmx - qmn + 1e-8f);
    const float qn[3] = {(qv.y - qmn) * qsc, (qv.z - qmn) * qsc, (qv.w - qmn) * qsc};
#pragma unroll
    for (int w = 0; w < 3; ++w) {
      const float th = params[w + 1];
      qA[il][w] = cosf(th) * cosf(qn[w]);
      qB[il][w] = sinf(th) * sinf(qn[w]);
    }
  }
  {  // V tile load (all threads)
    const int j0 = tid >> 5, d = tid & 31;
#pragma unroll
    for (int r = 0; r < 16; ++r) {
      const int j = r * 8 + j0;
      Vl[j][d] = V[(b * kS + j) * kD + h * 32 + d];
    }
  }
  __syncthreads();

  const int i_loc = tid >> 4;   // 0..15
  const int jl    = tid & 15;   // 16 threads per i-row
  const float A1 = qA[i_loc][0], A2 = qA[i_loc][1], A3 = qA[i_loc][2];
  const float B1 = qB[i_loc][0], B2 = qB[i_loc][1], B3 = qB[i_loc][2];

  float e[8];
  float mx = -1e30f;
#pragma unroll
  for (int jj = 0; jj < 8; ++jj) {
    const int j = jl + 16 * jj;
    const float v = (A1 - B1 * kC[0][j]) * (A2 - B2 * kC[1][j]) *
                    (A3 - B3 * kC[2][j]) * kScale;
    e[jj] = v;
    mx = fmaxf(mx, v);
  }
#pragma unroll
  for (int m = 1; m < 16; m <<= 1) mx = fmaxf(mx, __shfl_xor(mx, m, 16));
  float sum = 0.f;
#pragma unroll
  for (int jj = 0; jj < 8; ++jj) { e[jj] = expf(e[jj] - mx); sum += e[jj]; }
#pragma unroll
  for (int m = 1; m < 16; m <<= 1) sum += __shfl_xor(sum, m, 16);
  const float inv = 1.f / sum;
#pragma unroll
  for (int jj = 0; jj < 8; ++jj) pl[i_loc][jl + 16 * jj] = e[jj] * inv;
  __syncthreads();

  // attn @ V: thread -> (i = tid>>4, d0 = tid&15, and d0+16)
  const int d0 = tid & 15;
  float a0 = 0.f, a1 = 0.f;
#pragma unroll 4
  for (int j = 0; j < kS; ++j) {
    const float p = pl[i_loc][j];
    a0 = fmaf(p, Vl[j][d0], a0);
    a1 = fmaf(p, Vl[j][d0 + 16], a1);
  }
  const int base = (b * kS + i0 + i_loc) * kD + h * 32;
  const __bf16 h0 = (__bf16)a0;
  const __bf16 h1 = (__bf16)a1;
  aohi[base + d0]      = h0;
  aolo[base + d0]      = (__bf16)(a0 - (float)h0);
  aohi[base + d0 + 16] = h1;
  aolo[base + d0 + 16] = (__bf16)(a1 - (float)h1);
}

// ---- K3: out = ao @ Wo^T + bo, ao already bf16 hi/lo, Wo split inline -----
__global__ void out_gemm_kernel(const __bf16* __restrict__ aohi,
                                const __bf16* __restrict__ aolo,
                                const float* __restrict__ Wo,
                                const float* __restrict__ bo,
                                float* __restrict__ out) {
  const int wave = threadIdx.x >> 6;
  const int lane = threadIdx.x & 63;
  const int ln = lane & 15;
  const int qd = lane >> 4;
  const int m0 = blockIdx.x * 16;
  const int n0 = blockIdx.y * 64 + wave * 16;

  const __bf16* ap  = aohi + (m0 + ln) * kK + qd * 8;
  const __bf16* alp = aolo + (m0 + ln) * kK + qd * 8;
  const float*  bp  = Wo + (n0 + ln) * kK + qd * 8;

  f32x4 acc = {0.f, 0.f, 0.f, 0.f};
#pragma unroll
  for (int kc = 0; kc < kK; kc += 32) {
    const bf16x8 Ah = *(const bf16x8*)(ap  + kc);
    const bf16x8 Al = *(const bf16x8*)(alp + kc);
    bf16x8 Bh, Bl;
    split8(bp + kc, Bh, Bl);
    acc = __builtin_amdgcn_mfma_f32_16x16x32_bf16(Ah, Bh, acc, 0, 0, 0);
    acc = __builtin_amdgcn_mfma_f32_16x16x32_bf16(Ah, Bl, acc, 0, 0, 0);
    acc = __builtin_amdgcn_mfma_f32_16x16x32_bf16(Al, Bh, acc, 0, 0, 0);
  }
  const int col  = n0 + ln;
  const float bv = bo[col];
  const int row0 = m0 + qd * 4;
#pragma unroll
  for (int r = 0; r < 4; ++r)
    out[(row0 + r) * kD + col] = acc[r] + bv;
}

}  // namespace

extern "C" void kernel_launch(void* const* d_in, const int* in_sizes, int n_in,
                              void* d_out, int out_size, void* d_ws, size_t ws_size,
                              hipStream_t stream) {
  const float* x  = (const float*)d_in[0];
  const float* Wq = (const float*)d_in[1];
  const float* bq = (const float*)d_in[2];
  const float* Wk = (const float*)d_in[3];
  const float* bk = (const float*)d_in[4];
  const float* Wv = (const float*)d_in[5];
  const float* bv = (const float*)d_in[6];
  const float* Wo = (const float*)d_in[7];
  const float* bo = (const float*)d_in[8];
  const float* pr = (const float*)d_in[9];
  float* out = (float*)d_out;

  // -------- workspace layout (floats), all dedicated, no aliasing --------
  float* ws = (float*)d_ws;
  float* V   = ws;               // 131072
  float* Qs  = V + 131072;       // 16384 ([512][32] compact head-wire cols)
  float* Ks  = Qs + 16384;       // 16384
  __bf16* aohi = (__bf16*)(Ks + 16384);  // 131072 bf16
  __bf16* aolo = aohi + 131072;          // 131072 bf16
  // total ~0.9 MB << ws_size

  qkv_kernel<<<dim3(32, 5), 256, 0, stream>>>(x, Wq, bq, Wk, bk, Wv, bv, V, Qs, Ks);
  fused_attn_kernel<<<dim3(8, 32), 256, 0, stream>>>(Qs, Ks, V, pr, aohi, aolo);
  out_gemm_kernel<<<dim3(32, 4), 256, 0, stream>>>(aohi, aolo, Wo, bo, out);
}